// Round 11
// baseline (1068.236 us; speedup 1.0000x reference)
//
#include <hip/hip_runtime.h>

#define DIM 200
#define NENT 100000
#define NEDGE 1000000
#define EHALF 500000
#define NB 1024
#define NFILT 200
#define FLATSZ 39200

#define NDF ((size_t)NENT * DIM)
#define REGF ((size_t)20100000)

// fp16 weight panel image: 21 panels (seg*7+c), each 6656 halves:
//   [y0: rows 0..111][y1: rows 0..95], row = 32 halves, 16B-chunk index
//   XOR-swizzled by ((row>>1)&3)  (round-5/6 verified: 0 bank conflicts).
#define PANEL_TOT_H 6656
#define Y1OFF_H 3584
#define WT_TOTAL_H 139776      // 21 * 6656

typedef float floatx4 __attribute__((ext_vector_type(4)));
typedef _Float16 halfx8 __attribute__((ext_vector_type(8)));
typedef _Float16 halfx4 __attribute__((ext_vector_type(4)));

__device__ __forceinline__ void gAtomicAdd(float* p, float v) { unsafeAtomicAdd(p, v); }
__device__ __forceinline__ void gAtomicAdd(double* p, double v) { unsafeAtomicAdd(p, v); }

// async global -> LDS, 16B per lane (wave-uniform LDS base + lane*16)
__device__ __forceinline__ void gload16h(const _Float16* g, _Float16* l) {
    __builtin_amdgcn_global_load_lds(
        (const __attribute__((address_space(1))) void*)g,
        (__attribute__((address_space(3))) void*)l,
        16, 0, 0);
}

// ---------------------------------------------------------------- CSR build
__global__ __launch_bounds__(256) void edge_hist(
    const int* __restrict__ dst, int* __restrict__ hist)
{
    int stride = gridDim.x * blockDim.x;
    for (int e = blockIdx.x * 256 + threadIdx.x; e < NEDGE; e += stride)
        atomicAdd(&hist[dst[e]], 1);
}

__global__ __launch_bounds__(256) void scan1(
    const int* __restrict__ hist, int* __restrict__ incl, int* __restrict__ bsum)
{
    __shared__ int sm[256];
    int i = blockIdx.x * 256 + threadIdx.x;
    int t = threadIdx.x;
    sm[t] = (i < NENT) ? hist[i] : 0;
    __syncthreads();
    for (int off = 1; off < 256; off <<= 1) {
        int v = (t >= off) ? sm[t - off] : 0;
        __syncthreads();
        sm[t] += v;
        __syncthreads();
    }
    if (i < NENT) incl[i] = sm[t];
    if (t == 255) bsum[blockIdx.x] = sm[255];
}

__global__ __launch_bounds__(512) void scan2(int* bsum, int nb)
{
    __shared__ int sm[512];
    int t = threadIdx.x;
    int v = (t < nb) ? bsum[t] : 0;
    sm[t] = v;
    __syncthreads();
    for (int off = 1; off < 512; off <<= 1) {
        int u = (t >= off) ? sm[t - off] : 0;
        __syncthreads();
        sm[t] += u;
        __syncthreads();
    }
    if (t < nb) bsum[t] = sm[t] - v;
}

__global__ __launch_bounds__(256) void scan3(
    const int* __restrict__ hist, int* __restrict__ offs,
    const int* __restrict__ bsum, int* __restrict__ cursor)
{
    int i = blockIdx.x * 256 + threadIdx.x;
    if (i < NENT) {
        int excl = offs[i] - hist[i] + bsum[blockIdx.x];
        offs[i] = excl;
        cursor[i] = excl;
    }
    if (i == 0) offs[NENT] = NEDGE;
}

// rec: word0 = src*400 (byte offset) | invFlag<<31; word1 = etype | w_fp16<<16
__global__ __launch_bounds__(256) void edge_fill(
    const int* __restrict__ src, const int* __restrict__ dst,
    const int* __restrict__ etype, const float* __restrict__ enorm,
    int* __restrict__ cursor, uint2* __restrict__ recs)
{
    int stride = gridDim.x * blockDim.x;
    for (int e = blockIdx.x * 256 + threadIdx.x; e < NEDGE; e += stride) {
        int pos = atomicAdd(&cursor[dst[e]], 1);
        union { _Float16 h; unsigned short s; } wc;
        wc.h = (_Float16)enorm[e];
        unsigned a = (unsigned)(src[e] * 400) | ((e >= EHALF) ? 0x80000000u : 0u);
        unsigned b = (unsigned)etype[e] | ((unsigned)wc.s << 16);
        recs[pos] = make_uint2(a, b);
    }
}

__global__ __launch_bounds__(256) void build_map(
    const int* __restrict__ subj, const int* __restrict__ obj, int* __restrict__ map)
{
    int i = blockIdx.x * 256 + threadIdx.x;
    if (i < NB) map[subj[i]] = i;
    else if (i < 2 * NB) map[obj[i - NB]] = i;
}

// fp32 -> fp16 elementwise
__global__ __launch_bounds__(256) void to_f16(
    const float* __restrict__ X, _Float16* __restrict__ Y, long n4)
{
    long stride = (long)gridDim.x * blockDim.x;
    for (long i = (long)blockIdx.x * blockDim.x + threadIdx.x; i < n4; i += stride) {
        float4 v = ((const float4*)X)[i];
        halfx4 h;
        h[0] = (_Float16)v.x; h[1] = (_Float16)v.y;
        h[2] = (_Float16)v.z; h[3] = (_Float16)v.w;
        ((halfx4*)Y)[i] = h;
    }
}

// fp32 [200][200] -> fp16 padded [200][256] (512B row stride for 1-shift addressing)
__global__ __launch_bounds__(256) void to_f16_pad(
    const float* __restrict__ X, _Float16* __restrict__ Y)
{
    int i = blockIdx.x * 256 + threadIdx.x;
    if (i >= 40000) return;
    int row = i / 200, col = i - row * 200;
    Y[row * 256 + col] = (_Float16)X[i];
}

// ---------------------------------------------------------------- gather
// Scalarized CSR walk: node/beg/end/rec are wave-uniform (readfirstlane) ->
// rec loads go to the scalar pipe, loop control is scalar, in/out branch is
// a uniform s_cbranch.
__global__ __launch_bounds__(256) void gather_nodes(
    const _Float16* __restrict__ x16, const _Float16* __restrict__ r16p,
    const int* __restrict__ offs, const uint2* __restrict__ recs,
    _Float16* __restrict__ aggI, _Float16* __restrict__ aggO)
{
    int node = __builtin_amdgcn_readfirstlane(blockIdx.x * 4 + (threadIdx.x >> 6));
    int lane = threadIdx.x & 63;
    if (node >= NENT) return;
    int beg = offs[node], end = offs[node + 1];
    bool act = lane < 50;
    int lane_c = min(lane, 49);
    unsigned lo = (unsigned)(lane_c * 8);
    const char* xb = (const char*)x16;
    const char* rb = (const char*)r16p;
    halfx4 aI = (halfx4)0, aO = (halfx4)0;

    if (beg < end) {
        uint2 rcA = recs[beg];
        uint2 rcB = recs[min(beg + 1, end - 1)];
        halfx4 xvA = *(const halfx4*)(xb + ((rcA.x & 0x7FFFFFFFu) + lo));
        halfx4 rvA = *(const halfx4*)(rb + (((rcA.y & 0x1FFu) << 9) + lo));
        for (int i = beg; i < end; ++i) {
            uint2 rcC = recs[min(i + 2, end - 1)];
            halfx4 xvB = *(const halfx4*)(xb + ((rcB.x & 0x7FFFFFFFu) + lo));
            halfx4 rvB = *(const halfx4*)(rb + (((rcB.y & 0x1FFu) << 9) + lo));
            union { unsigned u; _Float16 h[2]; } wu; wu.u = rcA.y;
            _Float16 wh = wu.h[1];
            halfx4 w4 = {wh, wh, wh, wh};
            halfx4 comp = xvA * rvA;
            if ((int)rcA.x < 0) aO += comp * w4;   // inverse edge -> w_out path
            else aI += comp * w4;                  // forward edge -> w_in path
            rcA = rcB; rcB = rcC; xvA = xvB; rvA = rvB;
        }
    }
    if (act) {
        size_t base = (size_t)node * 200 + lane * 4;
        *(halfx4*)&aggI[base] = aI;
        *(halfx4*)&aggO[base] = aO;
    }
}

// ---------------------------------------------------------------- weight packing (fp16 panel + swizzle)
__global__ __launch_bounds__(256) void pack_w3(
    const float* __restrict__ w0, const float* __restrict__ w1,
    const float* __restrict__ w2, const float* __restrict__ lrel,
    _Float16* __restrict__ WpP)
{
    int i = blockIdx.x * 256 + threadIdx.x;
    if (i >= WT_TOTAL_H) return;
    int p = i / PANEL_TOT_H;
    int r = i % PANEL_TOT_H;
    int y = (r >= Y1OFF_H) ? 1 : 0;
    int rr = y ? (r - Y1OFF_H) : r;
    int rl = rr >> 5;
    int qx = (rr >> 3) & 3;
    int e = rr & 7;
    int q = qx ^ ((rl >> 1) & 3);
    int n = y * 112 + rl;
    int seg = p / 7, c = p - seg * 7;
    int k = c * 32 + q * 8 + e;
    const float* W = (seg == 0) ? w0 : (seg == 1) ? w1 : w2;
    float v = (n < 200 && k < 200) ? W[k * 200 + n] : 0.f;
    if (seg == 2 && n < 200 && k < 200) v *= lrel[k];
    WpP[i] = (_Float16)v;
}

__global__ __launch_bounds__(256) void pack_fcw(
    const float* __restrict__ W, _Float16* __restrict__ Wt)
{
    long i = (long)blockIdx.x * 256 + threadIdx.x;
    if (i >= (long)208 * FLATSZ) return;
    int n = (int)(i / FLATSZ);
    Wt[i] = (n < 200) ? (_Float16)W[i] : (_Float16)0.f;
}

// ---------------------------------------------------------------- fp16 MFMA GEMM, barrier-free K loop
template<int Y>
__global__ __launch_bounds__(1024) void gemm_big(
    const _Float16* __restrict__ A0h, const _Float16* __restrict__ A1h,
    const _Float16* __restrict__ A2h, const _Float16* __restrict__ WpP,
    float* __restrict__ C, const float* __restrict__ bias,
    const int* __restrict__ map, float alpha,
    double* __restrict__ s1, double* __restrict__ s2)
{
    constexpr int NF = Y ? 6 : 7;
    constexpr int PC = NF;                   // 1KB chunks per panel
    constexpr int PANEL_H = NF * 512;        // halves per panel (3584/3072)
    constexpr int YOFF_H = Y ? Y1OFF_H : 0;
    constexpr int SEG_LDS_H = 7 * PANEL_H;   // halves per seg buffer
    __shared__ _Float16 Sb[2 * SEG_LDS_H];   // 100352 B (Y=0) / 86016 B (Y=1)
    __shared__ float fsum[NF * 16];
    __shared__ float fsq[NF * 16];

    int tid = threadIdx.x;
    int lane = tid & 63, wave = tid >> 6;
    int col16 = lane & 15, quad = lane >> 4;
    if (tid < NF * 16) { fsum[tid] = 0.f; fsq[tid] = 0.f; }

    int gw = blockIdx.x * 16 + wave;         // 0..4095
    bool act = gw < 3125;                    // 3125 * 32 == 100000 exactly
    int t = act ? gw : 0;
    int r0 = t * 32 + col16, r1 = r0 + 16;
    size_t b0 = (size_t)r0 * 200, b1 = (size_t)r1 * 200;

    floatx4 acc[NF][2];
#pragma unroll
    for (int nf = 0; nf < NF; ++nf) { acc[nf][0] = (floatx4)0.f; acc[nf][1] = (floatx4)0.f; }

    halfx8 ca0, ca1, na0, na1;

    auto stage = [&](int seg, int bufi) {
        for (int cc = wave; cc < 7 * PC; cc += 16) {
            int p7 = cc / PC, sub = cc - p7 * PC;
            const _Float16* g = WpP + (size_t)(seg * 7 + p7) * PANEL_TOT_H
                              + YOFF_H + sub * 512 + lane * 8;
            gload16h(g, Sb + bufi * SEG_LDS_H + cc * 512);
        }
    };
    auto loadA = [&](int kc, halfx8& a0, halfx8& a1) {
        int seg = kc / 7, c = kc - seg * 7;
        int koff = c * 32 + quad * 8;
        if (koff < 200) {
            const _Float16* A = (seg == 0) ? A0h : (seg == 1) ? A1h : A2h;
            a0 = *(const halfx8*)&A[b0 + koff];
            a1 = *(const halfx8*)&A[b1 + koff];
        } else {
            a0 = (halfx8)0; a1 = (halfx8)0;
        }
    };

    stage(0, 0);
    if (act) loadA(0, ca0, ca1);
    __syncthreads();                         // publishes seg0 panel

    int buf = 0;
    for (int seg = 0; seg < 3; ++seg) {
        if (seg < 2) stage(seg + 1, buf ^ 1);   // async, overlaps MFMAs below
        if (act) {
#pragma unroll
            for (int c = 0; c < 7; ++c) {
                int kc = seg * 7 + c;
                if (kc < 20) loadA(kc + 1, na0, na1);
                const _Float16* P = Sb + buf * SEG_LDS_H + c * PANEL_H;
                __builtin_amdgcn_s_setprio(1);
#pragma unroll
                for (int nf = 0; nf < NF; ++nf) {
                    int rl = nf * 16 + col16;
                    int qs = quad ^ ((rl >> 1) & 3);
                    halfx8 b = *(const halfx8*)&P[rl * 32 + qs * 8];
                    acc[nf][0] = __builtin_amdgcn_mfma_f32_16x16x32_f16(ca0, b, acc[nf][0], 0, 0, 0);
                    acc[nf][1] = __builtin_amdgcn_mfma_f32_16x16x32_f16(ca1, b, acc[nf][1], 0, 0, 0);
                }
                __builtin_amdgcn_s_setprio(0);
                ca0 = na0; ca1 = na1;
            }
        }
        __syncthreads();                     // seg done; next-seg panel published
        buf ^= 1;
    }

    int slot[2][4];
    if (map && act) {
#pragma unroll
        for (int h = 0; h < 2; ++h)
#pragma unroll
            for (int j = 0; j < 4; ++j)
                slot[h][j] = map[t * 32 + h * 16 + quad * 4 + j];
    }
    if (act) {
#pragma unroll
        for (int nf = 0; nf < NF; ++nf) {
            int lc = nf * 16 + col16;
            int colg = Y * 112 + lc;
            float ls = 0.f, lq = 0.f;
            if (colg < 200) {
                float bv = bias[colg];
#pragma unroll
                for (int h = 0; h < 2; ++h) {
                    int rbase = t * 32 + h * 16 + quad * 4;
#pragma unroll
                    for (int j = 0; j < 4; ++j) {
                        float v = acc[nf][h][j] * alpha + bv;
                        ls += v; lq += v * v;
                        if (!map) {
                            C[(size_t)(rbase + j) * 200 + colg] = v;
                        } else {
                            int s = slot[h][j];
                            if (s >= 0) C[(size_t)s * 200 + colg] = v;
                        }
                    }
                }
            }
            ls += __shfl_down(ls, 32); ls += __shfl_down(ls, 16);
            lq += __shfl_down(lq, 32); lq += __shfl_down(lq, 16);
            if (quad == 0 && colg < 200) {
                atomicAdd(&fsum[lc], ls);
                atomicAdd(&fsq[lc], lq);
            }
        }
    }
    __syncthreads();
    if (tid < NF * 16) {
        int colg = Y * 112 + tid;
        if (colg < 200) {
            gAtomicAdd(&s1[colg], (double)fsum[tid]);
            gAtomicAdd(&s2[colg], (double)fsq[tid]);
        }
    }
}

// ---------------------------------------------------------------- fc MFMA GEMM body (fp16)
template<int NF0, int NF>
__device__ __forceinline__ void fc_gemm_body(
    const _Float16* __restrict__ Ph, const _Float16* __restrict__ Wt,
    float* __restrict__ part, int ky, _Float16* Bs)
{
    int t = threadIdx.x;
    int lane = t & 63, wave = t >> 6;
    int col16 = lane & 15, quad = lane >> 4;
    int row_base = blockIdx.x * 128 + wave * 32;
    int c0 = ky * 25;
    floatx4 acc[NF][2];
#pragma unroll
    for (int nf = 0; nf < NF; ++nf) { acc[nf][0] = (floatx4)0.f; acc[nf][1] = (floatx4)0.f; }
    int r0 = row_base + col16, r1 = row_base + 16 + col16;
    const int rows4 = NF * 16 * 4;

    for (int c = c0; c < c0 + 25; ++c) {
        int k0 = c * 32;
        for (int i = t; i < rows4; i += 256) {
            int nl = i >> 2, part_i = i & 3;
            int n = NF0 * 16 + nl;
            *(halfx8*)&Bs[nl * 40 + part_i * 8] =
                *(const halfx8*)&Wt[(size_t)n * FLATSZ + k0 + part_i * 8];
        }
        __syncthreads();
        int koff = k0 + quad * 8;
        halfx8 a0 = *(const halfx8*)&Ph[(size_t)r0 * FLATSZ + koff];
        halfx8 a1 = *(const halfx8*)&Ph[(size_t)r1 * FLATSZ + koff];
#pragma unroll
        for (int nf = 0; nf < NF; ++nf) {
            halfx8 b = *(const halfx8*)&Bs[(nf * 16 + col16) * 40 + quad * 8];
            acc[nf][0] = __builtin_amdgcn_mfma_f32_16x16x32_f16(a0, b, acc[nf][0], 0, 0, 0);
            acc[nf][1] = __builtin_amdgcn_mfma_f32_16x16x32_f16(a1, b, acc[nf][1], 0, 0, 0);
        }
        __syncthreads();
    }
    float* out = part + (size_t)ky * (NB * 200);
#pragma unroll
    for (int nf = 0; nf < NF; ++nf) {
        int colg = NF0 * 16 + nf * 16 + col16;
        if (colg >= 200) continue;
#pragma unroll
        for (int h = 0; h < 2; ++h) {
            int rbase = row_base + h * 16 + quad * 4;
#pragma unroll
            for (int j = 0; j < 4; ++j)
                out[(size_t)(rbase + j) * 200 + colg] = acc[nf][h][j];
        }
    }
}

__global__ __launch_bounds__(256) void fc_gemm(
    const _Float16* __restrict__ Ph, const _Float16* __restrict__ Wt,
    float* __restrict__ part)
{
    __shared__ _Float16 Bs[112 * 40];
    int ky = blockIdx.y >> 1;
    if ((blockIdx.y & 1) == 0)
        fc_gemm_body<0, 7>(Ph, Wt, part, ky, Bs);
    else
        fc_gemm_body<7, 6>(Ph, Wt, part, ky, Bs);
}

__global__ __launch_bounds__(256) void fc_reduce(
    const float* __restrict__ part, const float* __restrict__ bias,
    float* __restrict__ hfc)
{
    int i = blockIdx.x * 256 + threadIdx.x;
    float acc = bias[i % 200];
#pragma unroll
    for (int y = 0; y < 49; ++y) acc += part[(size_t)y * (NB * 200) + i];
    hfc[i] = acc;
}

// ---------------------------------------------------------------- stats / bn
__global__ __launch_bounds__(256) void colstats(
    const float* __restrict__ X, int M, int rpb,
    double* __restrict__ s1, double* __restrict__ s2)
{
    int c = threadIdx.x;
    if (c >= 200) return;
    int r0 = blockIdx.x * rpb;
    int r1 = min(r0 + rpb, M);
    float sum = 0.f, sq = 0.f;
    for (int rr = r0; rr < r1; ++rr) {
        float v = X[(size_t)rr * 200 + c];
        sum += v; sq += v * v;
    }
    gAtomicAdd(&s1[c], (double)sum);
    gAtomicAdd(&s2[c], (double)sq);
}

__global__ void finalize_stats(const double* __restrict__ s1, const double* __restrict__ s2,
                               const float* __restrict__ g, const float* __restrict__ bb,
                               float* __restrict__ sc, float* __restrict__ sh,
                               int ncols, double count)
{
    int c = threadIdx.x;
    if (c >= ncols) return;
    double m = s1[c] / count;
    double v = s2[c] / count - m * m;
    double scd = (double)g[c] / sqrt(v + 1e-5);
    sc[c] = (float)scd;
    sh[c] = (float)((double)bb[c] - m * scd);
}

// bn + tanh, fp32 in -> fp16 out (layer-1 x for gather + gemm A2)
__global__ __launch_bounds__(256) void bn_tanh_f16(
    const float* __restrict__ X, const float* __restrict__ sc,
    const float* __restrict__ sh, _Float16* __restrict__ Y, long n4)
{
    long stride = (long)gridDim.x * blockDim.x;
    for (long i = (long)blockIdx.x * blockDim.x + threadIdx.x; i < n4; i += stride) {
        int c4 = (int)(i % 50) * 4;
        float4 v = ((const float4*)X)[i];
        halfx4 h;
        h[0] = (_Float16)tanhf(v.x * sc[c4 + 0] + sh[c4 + 0]);
        h[1] = (_Float16)tanhf(v.y * sc[c4 + 1] + sh[c4 + 1]);
        h[2] = (_Float16)tanhf(v.z * sc[c4 + 2] + sh[c4 + 2]);
        h[3] = (_Float16)tanhf(v.w * sc[c4 + 3] + sh[c4 + 3]);
        ((halfx4*)Y)[i] = h;
    }
}

__global__ __launch_bounds__(256) void bn_act_200(
    float* __restrict__ X, const float* __restrict__ sc, const float* __restrict__ sh,
    long n4, int act)
{
    long stride = (long)gridDim.x * blockDim.x;
    for (long i = (long)blockIdx.x * blockDim.x + threadIdx.x; i < n4; i += stride) {
        int c4 = (int)(i % 50) * 4;
        float4 v = ((const float4*)X)[i];
        float a0 = v.x * sc[c4 + 0] + sh[c4 + 0];
        float a1 = v.y * sc[c4 + 1] + sh[c4 + 1];
        float a2 = v.z * sc[c4 + 2] + sh[c4 + 2];
        float a3 = v.w * sc[c4 + 3] + sh[c4 + 3];
        if (act == 0) { a0 = tanhf(a0); a1 = tanhf(a1); a2 = tanhf(a2); a3 = tanhf(a3); }
        else { a0 = fmaxf(a0, 0.f); a1 = fmaxf(a1, 0.f); a2 = fmaxf(a2, 0.f); a3 = fmaxf(a3, 0.f); }
        ((float4*)X)[i] = make_float4(a0, a1, a2, a3);
    }
}

__global__ __launch_bounds__(256) void rel_mm(
    const float* __restrict__ R, const float* __restrict__ W, float* __restrict__ O)
{
    int idx = blockIdx.x * blockDim.x + threadIdx.x;
    if (idx >= 200 * 200) return;
    int row = idx / 200, col = idx - row * 200;
    float acc = 0.f;
    for (int k = 0; k < 200; ++k) acc = fmaf(R[row * 200 + k], W[k * 200 + col], acc);
    O[idx] = acc;
}

__global__ __launch_bounds__(256) void build_stk(
    const float* __restrict__ x2c, const float* __restrict__ r2,
    const int* __restrict__ subj, const int* __restrict__ ridx,
    const int* __restrict__ map,
    float* __restrict__ stk, double* __restrict__ s1, double* __restrict__ s2)
{
    __shared__ float wsum[4], wsq[4];
    int b = blockIdx.x, t = threadIdx.x;
    const float* se = x2c + (size_t)map[subj[b]] * DIM;
    const float* re = r2 + (size_t)ridx[b] * DIM;
    float sum = 0.f, sq = 0.f;
    for (int i = t; i < 400; i += 256) {
        float v = (i < 200) ? se[i] : re[i - 200];
        stk[(size_t)b * 400 + i] = v;
        sum += v; sq += v * v;
    }
    for (int off = 32; off > 0; off >>= 1) {
        sum += __shfl_down(sum, off);
        sq  += __shfl_down(sq, off);
    }
    if ((t & 63) == 0) { wsum[t >> 6] = sum; wsq[t >> 6] = sq; }
    __syncthreads();
    if (t == 0) {
        float S = wsum[0] + wsum[1] + wsum[2] + wsum[3];
        float Q = wsq[0] + wsq[1] + wsq[2] + wsq[3];
        gAtomicAdd(&s1[0], (double)S);
        gAtomicAdd(&s2[0], (double)Q);
    }
}

// ---------------------------------------------------------------- conv: one thread = one filter
// All lanes read the SAME img address per step -> pure LDS broadcast, 0 bank
// conflicts. 49 weights in registers (no wsm LDS), stats in registers with
// ONE global atomic per thread. LDS = img only (1.6 KB). Identical FMA order.
__global__ __launch_bounds__(256) void conv_fwd(
    const float* __restrict__ stk, const float* __restrict__ conv_w,
    const float* __restrict__ conv_b, const float* __restrict__ sc0,
    const float* __restrict__ sh0, _Float16* __restrict__ Ph,
    double* __restrict__ s1, double* __restrict__ s2)
{
    __shared__ float img[400];
    int b = blockIdx.x, t = threadIdx.x;
    float scale0 = sc0[0], shift0 = sh0[0];
    for (int i = t; i < 400; i += 256)
        img[i] = stk[(size_t)b * 400 + i] * scale0 + shift0;
    __syncthreads();
    if (t >= 200) return;                    // no barriers after this point

    float w[49];
#pragma unroll
    for (int i = 0; i < 49; ++i) w[i] = conv_w[t * 49 + i];
    float bias = conv_b[t];
    float ls = 0.f, lq = 0.f;
    _Float16* pp = Ph + (size_t)b * FLATSZ + (size_t)t * 196;

    for (int y = 0; y < 14; ++y) {
        float acc[14];
#pragma unroll
        for (int xx = 0; xx < 14; ++xx) acc[xx] = bias;
#pragma unroll
        for (int i = 0; i < 7; ++i) {
            const float* rowp = &img[(y + i) * 20];
            float rv[20];
#pragma unroll
            for (int c4 = 0; c4 < 5; ++c4) {
                float4 v4 = *(const float4*)&rowp[c4 * 4];
                rv[c4 * 4 + 0] = v4.x; rv[c4 * 4 + 1] = v4.y;
                rv[c4 * 4 + 2] = v4.z; rv[c4 * 4 + 3] = v4.w;
            }
#pragma unroll
            for (int j = 0; j < 7; ++j) {
                float wv = w[i * 7 + j];
#pragma unroll
                for (int xx = 0; xx < 14; ++xx)
                    acc[xx] = fmaf(rv[xx + j], wv, acc[xx]);
            }
        }
#pragma unroll
        for (int xx = 0; xx < 14; ++xx) {
            float v = acc[xx];
            pp[y * 14 + xx] = (_Float16)v;
            ls += v; lq += v * v;
        }
    }
    gAtomicAdd(&s1[t], (double)ls);
    gAtomicAdd(&s2[t], (double)lq);
}

__global__ __launch_bounds__(256) void bn1_relu_f16(
    _Float16* __restrict__ Ph, const float* __restrict__ sc, const float* __restrict__ sh)
{
    long n4 = (long)NB * (FLATSZ / 4);
    long stride = (long)gridDim.x * blockDim.x;
    for (long i = (long)blockIdx.x * blockDim.x + threadIdx.x; i < n4; i += stride) {
        int k4 = (int)(i % (FLATSZ / 4));
        int f = k4 / 49;
        float s = sc[f], h = sh[f];
        halfx4 v = ((const halfx4*)Ph)[i];
#pragma unroll
        for (int e = 0; e < 4; ++e) {
            float x = (float)v[e];
            x = fmaxf(x * s + h, 0.f);
            v[e] = (_Float16)x;
        }
        ((halfx4*)Ph)[i] = v;
    }
}

__global__ __launch_bounds__(256) void score_mm(
    const float* __restrict__ Hn, const float* __restrict__ x2c,
    const int* __restrict__ obj, const int* __restrict__ map,
    float* __restrict__ out)
{
    __shared__ float Asm[16][17];
    __shared__ float Bsm[16][17];
    int tx = threadIdx.x & 15, ty = threadIdx.x >> 4;
    int row = blockIdx.y * 16 + ty;
    int col = blockIdx.x * 16 + tx;
    int oj = map[obj[blockIdx.x * 16 + ty]];
    float acc = 0.f;
    for (int k0 = 0; k0 < 200; k0 += 16) {
        int k = k0 + tx;
        Asm[ty][tx] = (k < 200) ? Hn[(size_t)row * 200 + k] : 0.f;
        Bsm[ty][tx] = (k < 200) ? x2c[(size_t)oj * 200 + k] : 0.f;
        __syncthreads();
#pragma unroll
        for (int kk = 0; kk < 16; ++kk) acc = fmaf(Asm[ty][kk], Bsm[tx][kk], acc);
        __syncthreads();
    }
    out[(size_t)row * NB + col] = 1.f / (1.f + expf(-acc));
}

// ---------------------------------------------------------------- driver
extern "C" void kernel_launch(void* const* d_in, const int* in_sizes, int n_in,
                              void* d_out, int out_size, void* d_ws, size_t ws_size,
                              hipStream_t stream)
{
    (void)in_sizes; (void)n_in; (void)out_size;
    const float* init_embed = (const float*)d_in[0];
    const float* init_rel   = (const float*)d_in[1];
    const float* edge_norm  = (const float*)d_in[2];
    const float* w_in1  = (const float*)d_in[3];
    const float* w_out1 = (const float*)d_in[4];
    const float* w_loop1= (const float*)d_in[5];
    const float* w_rel1 = (const float*)d_in[6];
    const float* lrel1  = (const float*)d_in[7];
    const float* b1     = (const float*)d_in[8];
    const float* gm1    = (const float*)d_in[9];
    const float* be1    = (const float*)d_in[10];
    const float* w_in2  = (const float*)d_in[11];
    const float* w_out2 = (const float*)d_in[12];
    const float* w_loop2= (const float*)d_in[13];
    const float* w_rel2 = (const float*)d_in[14];
    const float* lrel2  = (const float*)d_in[15];
    const float* b2     = (const float*)d_in[16];
    const float* gm2    = (const float*)d_in[17];
    const float* be2    = (const float*)d_in[18];
    const float* conv_w = (const float*)d_in[19];
    const float* conv_b = (const float*)d_in[20];
    const float* fc_w   = (const float*)d_in[21];
    const float* fc_b   = (const float*)d_in[22];
    const float* bn0_g  = (const float*)d_in[23];
    const float* bn0_b  = (const float*)d_in[24];
    const float* bn1_g  = (const float*)d_in[25];
    const float* bn1_b  = (const float*)d_in[26];
    const float* bn2_g  = (const float*)d_in[27];
    const float* bn2_b  = (const float*)d_in[28];
    const int* subj   = (const int*)d_in[29];
    const int* relidx = (const int*)d_in[30];
    const int* obj    = (const int*)d_in[31];
    const int* src    = (const int*)d_in[32];
    const int* dst    = (const int*)d_in[33];
    const int* etype  = (const int*)d_in[34];

    float* ws = (float*)d_ws;
    float* R0 = ws;                 // L1: x1f (C); L2: aggI2; head: Ph
    float* R1 = ws + REGF;          // L1: aggI1 (1st half) + ie16 (2nd half); then x1h
    float* R2 = ws + 2 * REGF;      // aggO (both layers); head: fch + fpart
    float* p = ws + 3 * REGF;       // tail
    float* r1v = p;            p += 40000;
    float* r2v = p;            p += 40000;
    float* stk = p;            p += 409600;
    float* hfc = p;            p += 204800;
    float* x2c = p;            p += 409600;
    float* fsc = p;            p += 256;
    float* fsh = p;            p += 256;
    double* ds1 = (double*)p;  p += 512;
    double* ds2 = (double*)p;  p += 512;
    _Float16* Wp = (_Float16*)p; p += (WT_TOTAL_H + 1) / 2;
    _Float16* rg16p = (_Float16*)p; p += 25600;  // fp16 rel table, 256-half row stride
    int* map = (int*)p;        p += NENT;
    int* hist = (int*)p;       p += NENT;
    int* offs = (int*)p;       p += NENT + 4;
    int* cursor = (int*)p;     p += NENT;
    int* bsum = (int*)p;       p += 512;
    uint2* recs = (uint2*)p;   p += (size_t)NEDGE * 2;

    float* x1f = R0;                           // L1 gemm C (fp32)
    _Float16* aggI1 = (_Float16*)R1;           // L1 aggI (fp16, 20M halves)
    _Float16* ie16  = (_Float16*)(R1 + 10050000); // fp16 init_embed (A2 for L1)
    _Float16* aggOh = (_Float16*)R2;           // agg-out fp16 (both layers)
    _Float16* x1h = (_Float16*)R1;             // fp16 x1 (aggI1/ie16 dead after L1 gemm)
    _Float16* aggI2 = (_Float16*)R0;           // L2 aggI (x1f dead after bn_tanh_f16)
    _Float16* Ph  = (_Float16*)R0;
    _Float16* fch = (_Float16*)R2;
    float* fpart = R2 + 4200000;

    const size_t NEED = (size_t)(p - ws) * sizeof(float);
    if (ws_size < NEED) return;

    const int NBLK = (NENT + 255) / 256;
    const size_t DSBYTES = 512 * sizeof(double);

    // -------- CSR build + slot map --------
    hipMemsetAsync(hist, 0, NENT * sizeof(int), stream);
    hipMemsetAsync(map, 0xFF, NENT * sizeof(int), stream);
    edge_hist<<<1024, 256, 0, stream>>>(dst, hist);
    scan1<<<NBLK, 256, 0, stream>>>(hist, offs, bsum);
    scan2<<<1, 512, 0, stream>>>(bsum, NBLK);
    scan3<<<NBLK, 256, 0, stream>>>(hist, offs, bsum, cursor);
    edge_fill<<<1024, 256, 0, stream>>>(src, dst, etype, edge_norm, cursor, recs);
    build_map<<<(2 * NB + 255) / 256, 256, 0, stream>>>(subj, obj, map);

    const int PACK_BLKS = (WT_TOTAL_H + 255) / 256;

    // -------- layer 1 --------
    pack_w3<<<PACK_BLKS, 256, 0, stream>>>(w_in1, w_out1, w_loop1, lrel1, Wp);
    to_f16<<<4096, 256, 0, stream>>>(init_embed, ie16, (long)NENT * 50);
    to_f16_pad<<<157, 256, 0, stream>>>(init_rel, rg16p);
    gather_nodes<<<(NENT + 3) / 4, 256, 0, stream>>>(ie16, rg16p, offs, recs,
                                                     aggI1, aggOh);
    hipMemsetAsync(ds1, 0, DSBYTES, stream);
    gemm_big<0><<<256, 1024, 0, stream>>>(aggI1, aggOh, ie16, Wp,
                                          x1f, b1, nullptr, 1.f / 3.f, ds1, ds2);
    gemm_big<1><<<256, 1024, 0, stream>>>(aggI1, aggOh, ie16, Wp,
                                          x1f, b1, nullptr, 1.f / 3.f, ds1, ds2);
    finalize_stats<<<1, 256, 0, stream>>>(ds1, ds2, gm1, be1, fsc, fsh, 200, (double)NENT);
    bn_tanh_f16<<<4096, 256, 0, stream>>>(x1f, fsc, fsh, x1h, (long)NENT * 50);
    rel_mm<<<(40000 + 255) / 256, 256, 0, stream>>>(init_rel, w_rel1, r1v);

    // -------- layer 2 (fp16 x; compact output) --------
    pack_w3<<<PACK_BLKS, 256, 0, stream>>>(w_in2, w_out2, w_loop2, lrel2, Wp);
    to_f16_pad<<<157, 256, 0, stream>>>(r1v, rg16p);
    gather_nodes<<<(NENT + 3) / 4, 256, 0, stream>>>(x1h, rg16p, offs, recs,
                                                     aggI2, aggOh);
    hipMemsetAsync(ds1, 0, DSBYTES, stream);
    gemm_big<0><<<256, 1024, 0, stream>>>(aggI2, aggOh, x1h, Wp,
                                          x2c, b2, map, 1.f / 3.f, ds1, ds2);
    gemm_big<1><<<256, 1024, 0, stream>>>(aggI2, aggOh, x1h, Wp,
                                          x2c, b2, map, 1.f / 3.f, ds1, ds2);
    finalize_stats<<<1, 256, 0, stream>>>(ds1, ds2, gm2, be2, fsc, fsh, 200, (double)NENT);
    bn_act_200<<<400, 256, 0, stream>>>(x2c, fsc, fsh, (long)2 * NB * 50, 0);
    rel_mm<<<(40000 + 255) / 256, 256, 0, stream>>>(r1v, w_rel2, r2v);

    // -------- ConvE head --------
    hipMemsetAsync(ds1, 0, DSBYTES, stream);
    build_stk<<<NB, 256, 0, stream>>>(x2c, r2v, subj, relidx, map, stk, ds1, ds2);
    finalize_stats<<<1, 256, 0, stream>>>(ds1, ds2, bn0_g, bn0_b, fsc, fsh, 1,
                                          (double)((long)NB * 400));
    hipMemsetAsync(ds1, 0, DSBYTES, stream);
    conv_fwd<<<NB, 256, 0, stream>>>(stk, conv_w, conv_b, fsc, fsh, Ph, ds1, ds2);
    finalize_stats<<<1, 256, 0, stream>>>(ds1, ds2, bn1_g, bn1_b, fsc, fsh, 200,
                                          (double)((long)NB * 196));
    bn1_relu_f16<<<4096, 256, 0, stream>>>(Ph, fsc, fsh);
    pack_fcw<<<(int)(((long)208 * FLATSZ + 255) / 256), 256, 0, stream>>>(fc_w, fch);
    fc_gemm<<<dim3(8, 98), 256, 0, stream>>>(Ph, fch, fpart);
    fc_reduce<<<800, 256, 0, stream>>>(fpart, fc_b, hfc);
    hipMemsetAsync(ds1, 0, DSBYTES, stream);
    colstats<<<4, 256, 0, stream>>>(hfc, NB, 256, ds1, ds2);
    finalize_stats<<<1, 256, 0, stream>>>(ds1, ds2, bn2_g, bn2_b, fsc, fsh, 200, (double)NB);
    bn_act_200<<<200, 256, 0, stream>>>(hfc, fsc, fsh, (long)NB * 50, 1);
    score_mm<<<dim3(NB / 16, NB / 16), 256, 0, stream>>>(hfc, x2c, obj, map, (float*)d_out);
}